// Round 6
// baseline (237.601 us; speedup 1.0000x reference)
//
#include <hip/hip_runtime.h>
#include <stdint.h>

// ----------------------------------------------------------------------------
// SparseKVCache: keep top-k by |x| (k = n/2), zero the rest. Exact.
// R6: copy-shaped streaming kernels, exactness via 2-level refine.
//   sample (16MB, wave-contiguous) -> bracket [uLo,uHi)
//   pass1: read-only 128MB; exact cntHi + 1024-bin hist of bracket (0.9%)
//   sel2:  exact sub-bin [tLo,tHi2) containing the cut + remB (~300 elems)
//   pass2: out = (u>=tHi2)?v:0  (pure copy+cndmask); ~300 in-bin elements
//          pushed to global pairs via direct atomics (P~1e-5)
//   fixup: exact stable rank (val desc, idx asc) over pairs; keep rank<remB
// Deterministic: all atomics are counts or order-independent scatters.
// ----------------------------------------------------------------------------

#define NTHR 256
#define MASK31 0x7fffffffu

// ---- ws layout (uint32 words) ----
#define SH_OFF    0           // 8192-bin sample histogram (bits 30..18)
#define SH_BINS   8192
#define BH_OFF    8192        // 1024-bin bracket histogram (exact, pass1)
#define BH_BINS   1024
#define SCL_OFF   9216        // scalars:
//  [0]=uLo [1]=uHi [2]=shift1 [3]=cntHi [4]=pairCnt [5]=tLo [6]=tHi2 [7]=remB
#define PAIRS_OFF 9232        // pairs (uint2); even word => 8B aligned
#define PAIRS_CAP 8192
#define ZERO_WORDS (SCL_OFF + 16)

__global__ void zero_ws_kernel(uint32_t* __restrict__ ws) {
    int i = blockIdx.x * blockDim.x + threadIdx.x;
    if (i < ZERO_WORDS) ws[i] = 0;
}

// ---- sample histogram: 64 contiguous uint4 per wave, phase-rotated groups --
__global__ void sample_hist_kernel(const uint4* __restrict__ xv, long long n4,
                                   uint32_t* __restrict__ ws) {
    __shared__ uint32_t lh[SH_BINS];
    for (int i = threadIdx.x; i < SH_BINS; i += NTHR) lh[i] = 0;
    __syncthreads();
    long long S4 = n4 >> 5;                    // sampled uint4 count (1/32)
    long long T = (long long)gridDim.x * NTHR;
    for (long long s = (long long)blockIdx.x * NTHR + threadIdx.x; s < S4; s += T) {
        long long g = s >> 6;                  // group of 64 consecutive uint4
        long long idx4 = g * 2048 + ((g & 31) << 6) + (s & 63);
        uint4 v = xv[idx4];
        atomicAdd(&lh[(v.x & MASK31) >> 18], 1u);
        atomicAdd(&lh[(v.y & MASK31) >> 18], 1u);
        atomicAdd(&lh[(v.z & MASK31) >> 18], 1u);
        atomicAdd(&lh[(v.w & MASK31) >> 18], 1u);
    }
    __syncthreads();
    for (int i = threadIdx.x; i < SH_BINS; i += NTHR)
        if (lh[i]) atomicAdd(&ws[SH_OFF + i], lh[i]);
}

// ---- bracket select from sample histogram -> value-space [uLo, uHi) --------
__global__ void sel_bracket_kernel(uint32_t* __restrict__ ws,
                                   uint32_t ksmM, uint32_t kspM) {
    __shared__ uint32_t lh[SH_BINS];
    __shared__ uint32_t csum[NTHR];
    __shared__ uint32_t cpre[NTHR];
    __shared__ int sBHi, sB1;
    for (int i = threadIdx.x; i < SH_BINS; i += NTHR) lh[i] = ws[SH_OFF + i];
    if (threadIdx.x == 0) { sBHi = -1; sB1 = -1; }
    __syncthreads();
    uint32_t s = 0;
    for (int i = 0; i < 32; ++i) s += lh[threadIdx.x * 32 + i];
    csum[threadIdx.x] = s;
    __syncthreads();
    if (threadIdx.x == 0) {
        uint32_t run = 0;
        for (int c = NTHR - 1; c >= 0; --c) { cpre[c] = run; run += csum[c]; }
    }
    __syncthreads();
    {
        int c = threadIdx.x;
        int hitHi = -1, hitB1 = -1;
        uint32_t excl = cpre[c];
        for (int bb = c * 32 + 31; bb >= c * 32; --bb) {
            uint32_t cnt = lh[bb];
            uint32_t incl = excl + cnt;
            if (hitHi < 0 && incl >= ksmM) hitHi = bb;
            if (hitB1 < 0 && excl >= kspM) hitB1 = bb;
            excl = incl;
        }
        if (hitHi >= 0) atomicMax(&sBHi, hitHi);
        if (hitB1 >= 0) atomicMax(&sB1, hitB1);
    }
    __syncthreads();
    if (threadIdx.x == 0) {
        int bHi = sBHi < 0 ? 0 : sBHi;
        int bLo = sB1 + 1;
        if (bLo > bHi) bLo = bHi;
        if (bLo < 0) bLo = 0;
        int sbins = bHi - bLo + 1;
        int clog = 0; while ((1 << clog) < sbins) ++clog;
        int spanBits = 18 + clog;
        int shift1 = spanBits - 10;            // 1024 bins over the span
        if (shift1 < 0) shift1 = 0;
        ws[SCL_OFF + 0] = ((uint32_t)bLo) << 18;          // uLo
        ws[SCL_OFF + 1] = ((uint32_t)(bHi + 1)) << 18;    // uHi (exclusive)
        ws[SCL_OFF + 2] = (uint32_t)shift1;
    }
}

// ---- pass1: read-only; exact cntHi + bracket histogram ----------------------
__global__ void pass1_hist_kernel(const uint32_t* __restrict__ x, long long n,
                                  uint32_t* __restrict__ ws) {
    __shared__ uint32_t lh[BH_BINS];
    for (int i = threadIdx.x; i < BH_BINS; i += NTHR) lh[i] = 0;
    __syncthreads();
    const uint32_t uLo = ws[SCL_OFF + 0];
    const uint32_t uHi = ws[SCL_OFF + 1];
    const uint32_t shift1 = ws[SCL_OFF + 2];
    const uint32_t span = uHi - uLo;
    uint32_t myHi = 0;

#define DOH(comp) { uint32_t u_ = (comp) & MASK31; \
    myHi += (u_ >= uHi) ? 1u : 0u; \
    uint32_t d_ = u_ - uLo; \
    if (d_ < span) atomicAdd(&lh[(d_ >> shift1) & (BH_BINS - 1)], 1u); }

    long long n4 = n >> 2;
    const uint4* __restrict__ xv = (const uint4*)x;
    long long stride = (long long)gridDim.x * NTHR;
    for (long long i = (long long)blockIdx.x * NTHR + threadIdx.x; i < n4; i += stride) {
        uint4 v = xv[i];
        DOH(v.x) DOH(v.y) DOH(v.z) DOH(v.w)
    }
    if (blockIdx.x == 0) {
        for (long long idx = (n4 << 2) + threadIdx.x; idx < n; idx += NTHR) {
            uint32_t v = x[idx];
            DOH(v)
        }
    }
#undef DOH
    // wave-level reduce of myHi, one global atomic per wave
    for (int o = 32; o > 0; o >>= 1) myHi += __shfl_down(myHi, o);
    if ((threadIdx.x & 63) == 0 && myHi) atomicAdd(&ws[SCL_OFF + 3], myHi);
    __syncthreads();
    for (int i = threadIdx.x; i < BH_BINS; i += NTHR)
        if (lh[i]) atomicAdd(&ws[BH_OFF + i], lh[i]);
}

// ---- sel2: exact sub-bin containing the cut ---------------------------------
__global__ void sel2_kernel(uint32_t* __restrict__ ws, uint32_t k) {
    __shared__ uint32_t lh[BH_BINS];
    __shared__ uint32_t csum[NTHR];
    __shared__ uint32_t cpre[NTHR];
    __shared__ uint32_t sKp;
    for (int i = threadIdx.x; i < BH_BINS; i += NTHR) lh[i] = ws[BH_OFF + i];
    __syncthreads();
    const int cs = BH_BINS / NTHR;   // 4
    uint32_t s = 0;
    for (int i = 0; i < cs; ++i) s += lh[threadIdx.x * cs + i];
    csum[threadIdx.x] = s;
    __syncthreads();
    if (threadIdx.x == 0) {
        uint32_t run = 0;
        for (int c = NTHR - 1; c >= 0; --c) { cpre[c] = run; run += csum[c]; }
        uint32_t cntHi = ws[SCL_OFF + 3];
        uint32_t total = cpre[0] + csum[0];
        uint32_t kp = (k > cntHi) ? (k - cntHi) : 1u;   // safety clamps
        if (kp > total) kp = total;
        if (kp < 1u) kp = 1u;
        sKp = kp;
    }
    __syncthreads();
    uint32_t kp = sKp;
    if (cpre[threadIdx.x] < kp && kp <= cpre[threadIdx.x] + csum[threadIdx.x]) {
        uint32_t excl = cpre[threadIdx.x];
        for (int bb = threadIdx.x * cs + cs - 1; bb >= threadIdx.x * cs; --bb) {
            uint32_t cnt = lh[bb];
            if (excl + cnt >= kp) {
                uint32_t uLo = ws[SCL_OFF + 0], shift1 = ws[SCL_OFF + 2];
                uint32_t tLo = uLo + (((uint32_t)bb) << shift1);
                ws[SCL_OFF + 5] = tLo;
                ws[SCL_OFF + 6] = tLo + (1u << shift1);
                ws[SCL_OFF + 7] = kp - excl;
                break;
            }
            excl += cnt;
        }
    }
}

// ---- pass2: pure copy + cndmask; rare (P~1e-5) direct-global pair push ------
__global__ void pass2_out_kernel(const uint32_t* __restrict__ x,
                                 uint32_t* __restrict__ out, long long n,
                                 uint32_t* __restrict__ ws) {
    const uint32_t tLo = ws[SCL_OFF + 5];
    const uint32_t tHi2 = ws[SCL_OFF + 6];
    const uint32_t W = tHi2 - tLo;
    uint2* __restrict__ gpairs = (uint2*)(ws + PAIRS_OFF);

#define DOC(comp, eidx) { uint32_t u_ = (comp) & MASK31; \
    if (u_ - tLo < W) { uint32_t p_ = atomicAdd(&ws[SCL_OFF + 4], 1u); \
        if (p_ < PAIRS_CAP) gpairs[p_] = make_uint2((comp), (eidx)); } \
    (comp) = (u_ >= tHi2) ? (comp) : 0u; }

    long long n4 = n >> 2;
    const uint4* __restrict__ xv = (const uint4*)x;
    uint4* __restrict__ ov = (uint4*)out;
    long long stride = (long long)gridDim.x * NTHR;
    for (long long i = (long long)blockIdx.x * NTHR + threadIdx.x; i < n4; i += stride) {
        uint4 v = xv[i];
        uint32_t e0 = (uint32_t)(i << 2);
        DOC(v.x, e0 + 0u) DOC(v.y, e0 + 1u) DOC(v.z, e0 + 2u) DOC(v.w, e0 + 3u)
        ov[i] = v;
    }
    if (blockIdx.x == 0) {
        for (long long idx = (n4 << 2) + threadIdx.x; idx < n; idx += NTHR) {
            uint32_t v = x[idx];
            DOC(v, (uint32_t)idx)
            out[idx] = v;
        }
    }
#undef DOC
}

// ---- final fixup: exact stable rank over pairs; scatter kept ones -----------
__global__ void final_fixup_kernel(uint32_t* __restrict__ ws,
                                   uint32_t* __restrict__ out) {
    __shared__ uint2 lp[PAIRS_CAP];   // 64 KB
    uint32_t m = ws[SCL_OFF + 4]; if (m > PAIRS_CAP) m = PAIRS_CAP;
    uint32_t remB = ws[SCL_OFF + 7];
    const uint2* __restrict__ gpairs = (const uint2*)(ws + PAIRS_OFF);
    for (uint32_t i = threadIdx.x; i < m; i += NTHR) lp[i] = gpairs[i];
    __syncthreads();
    for (uint32_t i = threadIdx.x; i < m; i += NTHR) {
        uint2 me = lp[i];
        uint32_t ui = me.x & MASK31;
        uint32_t rank = 0;
        for (uint32_t p = 0; p < m; ++p) {
            uint2 pr = lp[p];
            uint32_t up = pr.x & MASK31;
            rank += (up > ui || (up == ui && pr.y < me.y)) ? 1u : 0u;
        }
        if (rank < remB) out[me.y] = me.x;
    }
}

extern "C" void kernel_launch(void* const* d_in, const int* in_sizes, int n_in,
                              void* d_out, int out_size, void* d_ws, size_t ws_size,
                              hipStream_t stream) {
    const uint32_t* x = (const uint32_t*)d_in[0];
    uint32_t* out = (uint32_t*)d_out;
    uint32_t* ws = (uint32_t*)d_ws;
    long long n = (long long)in_sizes[0];

    const double ratio = 0.5;  // SPARSE_COMPRESSION_RATIO
    long long k = (long long)((double)n * (1.0 - ratio));
    if (k < 1) k = 1;
    if (k > n) k = n;

    long long n4 = n >> 2;
    long long S = (n4 >> 5) << 2;           // sampled elements (1/32 of n)
    long long ks = (long long)((double)k * ((double)S / (double)n));
    const long long M = 4500;               // ~9 sigma at S=1,048,576
    uint32_t ksmM = (uint32_t)((ks - M) < 1 ? 1 : (ks - M));
    uint32_t kspM = (uint32_t)((ks + M) > S ? S : (ks + M));

    zero_ws_kernel<<<(ZERO_WORDS + NTHR - 1) / NTHR, NTHR, 0, stream>>>(ws);
    sample_hist_kernel<<<256, NTHR, 0, stream>>>((const uint4*)x, n4, ws);
    sel_bracket_kernel<<<1, NTHR, 0, stream>>>(ws, ksmM, kspM);
    pass1_hist_kernel<<<2048, NTHR, 0, stream>>>(x, n, ws);
    sel2_kernel<<<1, NTHR, 0, stream>>>(ws, (uint32_t)k);
    pass2_out_kernel<<<2048, NTHR, 0, stream>>>(x, out, n, ws);
    final_fixup_kernel<<<1, NTHR, 0, stream>>>(ws, out);
}

// Round 7
// 153.111 us; speedup vs baseline: 1.5518x; 1.5518x over previous
//
#include <hip/hip_runtime.h>
#include <stdint.h>

// ----------------------------------------------------------------------------
// SparseKVCache: keep top-k by |x| (k = n/2), zero the rest. Exact.
// R7: ONE branchless copy-shaped fused pass (loads -> branchless classify ->
// stores; per-iteration hit bits), rare work (bracket gather, ~0.9%) deferred
// to a post-loop revisit of flagged iterations. Exact select on the gathered
// candidate set (multi-block), exact stable ties (smallest indices win) via
// rank fixup. Deterministic: pair order varies, results are order-independent.
// ----------------------------------------------------------------------------

#define NTHR 256
#define MASK31 0x7fffffffu

// ---- ws layout (uint32 words) ----
#define SH_OFF    0           // 8192-bin sample histogram (bits 30..18)
#define SH_BINS   8192
#define CH_OFF    8192        // 4096-bin candidate histogram
#define CH_BINS   4096
#define SCL_OFF   12288       // scalars:
//  [0]=uLo [1]=uHi [2]=shift1 [3]=cntHi [4]=gCount [5]=base2 [6]=rem2 [7]=c3
#define L3_OFF    12304       // sub-bin pairs (uint2); even => 8B aligned
#define L3_CAP    4096
#define PAIRS_OFF (L3_OFF + 2 * L3_CAP)    // 20496, even => 8B aligned
#define PAIRS_CAP (1u << 20)               // 1M pairs = 8 MB
#define ZERO_WORDS (SCL_OFF + 16)

#define STG_CAP   2048        // per-block LDS pair stage (16 KB)

__global__ void zero_ws_kernel(uint32_t* __restrict__ ws) {
    int i = blockIdx.x * blockDim.x + threadIdx.x;
    if (i < ZERO_WORDS) ws[i] = 0;
}

// ---- sample histogram: 64 contiguous uint4 per group, 1/32 of data ---------
__global__ void sample_hist_kernel(const uint4* __restrict__ xv, long long n4,
                                   uint32_t* __restrict__ ws) {
    __shared__ uint32_t lh[SH_BINS];
    for (int i = threadIdx.x; i < SH_BINS; i += NTHR) lh[i] = 0;
    __syncthreads();
    long long S4 = n4 >> 5;                    // sampled uint4 count (1/32)
    long long T = (long long)gridDim.x * NTHR;
    for (long long s = (long long)blockIdx.x * NTHR + threadIdx.x; s < S4; s += T) {
        long long g = s >> 6;                  // group of 64 consecutive uint4
        long long idx4 = g * 2048 + ((g & 31) << 6) + (s & 63);
        uint4 v = xv[idx4];
        atomicAdd(&lh[(v.x & MASK31) >> 18], 1u);
        atomicAdd(&lh[(v.y & MASK31) >> 18], 1u);
        atomicAdd(&lh[(v.z & MASK31) >> 18], 1u);
        atomicAdd(&lh[(v.w & MASK31) >> 18], 1u);
    }
    __syncthreads();
    for (int i = threadIdx.x; i < SH_BINS; i += NTHR)
        if (lh[i]) atomicAdd(&ws[SH_OFF + i], lh[i]);
}

// ---- bracket select from sample histogram -> value-space [uLo, uHi) --------
__global__ void sel_bracket_kernel(uint32_t* __restrict__ ws,
                                   uint32_t ksmM, uint32_t kspM) {
    __shared__ uint32_t lh[SH_BINS];
    __shared__ uint32_t csum[NTHR];
    __shared__ uint32_t cpre[NTHR];
    __shared__ int sBHi, sB1;
    for (int i = threadIdx.x; i < SH_BINS; i += NTHR) lh[i] = ws[SH_OFF + i];
    if (threadIdx.x == 0) { sBHi = -1; sB1 = -1; }
    __syncthreads();
    uint32_t s = 0;
    for (int i = 0; i < 32; ++i) s += lh[threadIdx.x * 32 + i];
    csum[threadIdx.x] = s;
    __syncthreads();
    if (threadIdx.x == 0) {
        uint32_t run = 0;
        for (int c = NTHR - 1; c >= 0; --c) { cpre[c] = run; run += csum[c]; }
    }
    __syncthreads();
    {
        int c = threadIdx.x;
        int hitHi = -1, hitB1 = -1;
        uint32_t excl = cpre[c];
        for (int bb = c * 32 + 31; bb >= c * 32; --bb) {
            uint32_t cnt = lh[bb];
            uint32_t incl = excl + cnt;
            if (hitHi < 0 && incl >= ksmM) hitHi = bb;
            if (hitB1 < 0 && excl >= kspM) hitB1 = bb;
            excl = incl;
        }
        if (hitHi >= 0) atomicMax(&sBHi, hitHi);
        if (hitB1 >= 0) atomicMax(&sB1, hitB1);
    }
    __syncthreads();
    if (threadIdx.x == 0) {
        int bHi = sBHi < 0 ? 0 : sBHi;
        int bLo = sB1 + 1;
        if (bLo > bHi) bLo = bHi;
        if (bLo < 0) bLo = 0;
        int sbins = bHi - bLo + 1;
        int clog = 0; while ((1 << clog) < sbins) ++clog;
        int spanBits = 18 + clog;
        int shift1 = spanBits - 12;            // 4096 bins over the span
        if (shift1 < 0) shift1 = 0;
        ws[SCL_OFF + 0] = ((uint32_t)bLo) << 18;          // uLo
        ws[SCL_OFF + 1] = ((uint32_t)(bHi + 1)) << 18;    // uHi (exclusive)
        ws[SCL_OFF + 2] = (uint32_t)shift1;
    }
}

// ---- fused full pass: branchless stream + deferred rare gather -------------
__global__ void fused_main_kernel(const uint32_t* __restrict__ x,
                                  uint32_t* __restrict__ out, long long n,
                                  uint32_t* __restrict__ ws) {
    __shared__ uint2 stage[STG_CAP];
    __shared__ uint32_t cnt, sBase, redHi[NTHR / 64];
    const uint32_t uLo = ws[SCL_OFF + 0];
    const uint32_t uHi = ws[SCL_OFF + 1];
    const uint32_t span = uHi - uLo;
    if (threadIdx.x == 0) cnt = 0u;
    __syncthreads();

    const uint4* __restrict__ xv = (const uint4*)x;
    uint4* __restrict__ ov = (uint4*)out;
    uint2* __restrict__ gpairs = (uint2*)(ws + PAIRS_OFF);
    long long n4 = n >> 2;
    const long long stride = (long long)gridDim.x * NTHR;
    const long long i0 = (long long)blockIdx.x * NTHR + threadIdx.x;

    uint32_t myHi = 0;
    uint32_t hitIter = 0;
    uint32_t it = 0;
    long long i = i0;
    // ---- hot loop: 2 independent loads, branchless body, 2 stores ----
    for (; i + stride < n4; i += 2 * stride, it += 2) {
        uint4 va = xv[i];
        uint4 vb = xv[i + stride];
        uint32_t a0 = va.x & MASK31, a1 = va.y & MASK31;
        uint32_t a2 = va.z & MASK31, a3 = va.w & MASK31;
        uint32_t b0 = vb.x & MASK31, b1 = vb.y & MASK31;
        uint32_t b2 = vb.z & MASK31, b3 = vb.w & MASK31;
        myHi += (uint32_t)(a0 >= uHi) + (uint32_t)(a1 >= uHi)
              + (uint32_t)(a2 >= uHi) + (uint32_t)(a3 >= uHi)
              + (uint32_t)(b0 >= uHi) + (uint32_t)(b1 >= uHi)
              + (uint32_t)(b2 >= uHi) + (uint32_t)(b3 >= uHi);
        uint32_t ha = (uint32_t)((a0 - uLo) < span) | (uint32_t)((a1 - uLo) < span)
                    | (uint32_t)((a2 - uLo) < span) | (uint32_t)((a3 - uLo) < span);
        uint32_t hb = (uint32_t)((b0 - uLo) < span) | (uint32_t)((b1 - uLo) < span)
                    | (uint32_t)((b2 - uLo) < span) | (uint32_t)((b3 - uLo) < span);
        hitIter |= ha << (it & 31);
        hitIter |= hb << ((it + 1) & 31);
        uint4 oa, ob;
        oa.x = (a0 >= uHi) ? va.x : 0u;
        oa.y = (a1 >= uHi) ? va.y : 0u;
        oa.z = (a2 >= uHi) ? va.z : 0u;
        oa.w = (a3 >= uHi) ? va.w : 0u;
        ob.x = (b0 >= uHi) ? vb.x : 0u;
        ob.y = (b1 >= uHi) ? vb.y : 0u;
        ob.z = (b2 >= uHi) ? vb.z : 0u;
        ob.w = (b3 >= uHi) ? vb.w : 0u;
        ov[i] = oa;
        ov[i + stride] = ob;
    }
    if (i < n4) {   // last single iteration
        uint4 v = xv[i];
        uint32_t a0 = v.x & MASK31, a1 = v.y & MASK31;
        uint32_t a2 = v.z & MASK31, a3 = v.w & MASK31;
        myHi += (uint32_t)(a0 >= uHi) + (uint32_t)(a1 >= uHi)
              + (uint32_t)(a2 >= uHi) + (uint32_t)(a3 >= uHi);
        uint32_t ha = (uint32_t)((a0 - uLo) < span) | (uint32_t)((a1 - uLo) < span)
                    | (uint32_t)((a2 - uLo) < span) | (uint32_t)((a3 - uLo) < span);
        hitIter |= ha << (it & 31);
        uint4 o;
        o.x = (a0 >= uHi) ? v.x : 0u;
        o.y = (a1 >= uHi) ? v.y : 0u;
        o.z = (a2 >= uHi) ? v.z : 0u;
        o.w = (a3 >= uHi) ? v.w : 0u;
        ov[i] = o;
    }

#define PUSHP(val, eidx) { \
    uint32_t p_ = atomicAdd(&cnt, 1u); \
    uint2 pr_ = make_uint2((val), (eidx)); \
    if (p_ < STG_CAP) stage[p_] = pr_; \
    else { uint32_t g_ = atomicAdd(&ws[SCL_OFF + 4], 1u); \
           if (g_ < PAIRS_CAP) gpairs[g_] = pr_; } }

    // ---- scalar tail (n & 3), block 0 ----
    if (blockIdx.x == 0) {
        for (long long idx = (n4 << 2) + threadIdx.x; idx < n; idx += NTHR) {
            uint32_t v = x[idx];
            uint32_t u = v & MASK31;
            myHi += (uint32_t)(u >= uHi);
            if (u - uLo < span) PUSHP(v, (uint32_t)idx)
            out[idx] = (u >= uHi) ? v : 0u;
        }
    }

    // ---- rare path: revisit flagged iterations (reloads are L2-hot) ----
    while (hitIter) {
        uint32_t b = __ffs(hitIter) - 1u;
        hitIter &= hitIter - 1u;
        for (long long ii = i0 + (long long)b * stride; ii < n4; ii += (stride << 5)) {
            uint4 v = xv[ii];
            uint32_t e0 = (uint32_t)(ii << 2);
            uint32_t u;
            u = v.x & MASK31; if (u - uLo < span) PUSHP(v.x, e0 + 0u)
            u = v.y & MASK31; if (u - uLo < span) PUSHP(v.y, e0 + 1u)
            u = v.z & MASK31; if (u - uLo < span) PUSHP(v.z, e0 + 2u)
            u = v.w & MASK31; if (u - uLo < span) PUSHP(v.w, e0 + 3u)
        }
    }
#undef PUSHP

    // ---- block-level cntHi reduce: one global atomic per block ----
    for (int o = 32; o > 0; o >>= 1) myHi += __shfl_down(myHi, o);
    if ((threadIdx.x & 63) == 0) redHi[threadIdx.x >> 6] = myHi;
    __syncthreads();
    if (threadIdx.x == 0) {
        uint32_t tot = 0;
        for (int w = 0; w < NTHR / 64; ++w) tot += redHi[w];
        if (tot) atomicAdd(&ws[SCL_OFF + 3], tot);
        uint32_t c = cnt < STG_CAP ? cnt : STG_CAP;
        cnt = c;
        sBase = atomicAdd(&ws[SCL_OFF + 4], c);
    }
    __syncthreads();
    uint32_t c = cnt, bw = sBase;
    for (uint32_t q = threadIdx.x; q < c; q += NTHR)
        if (bw + q < PAIRS_CAP) gpairs[bw + q] = stage[q];
}

// ---- candidate histogram (4096 bins over bracket) ---------------------------
__global__ void cand_hist_kernel(uint32_t* __restrict__ ws) {
    __shared__ uint32_t lh[CH_BINS];
    uint32_t G = ws[SCL_OFF + 4]; if (G > PAIRS_CAP) G = PAIRS_CAP;
    uint32_t uLo = ws[SCL_OFF + 0], shift1 = ws[SCL_OFF + 2];
    for (int i = threadIdx.x; i < CH_BINS; i += NTHR) lh[i] = 0;
    __syncthreads();
    const uint2* pairs = (const uint2*)(ws + PAIRS_OFF);
    uint32_t stride = gridDim.x * NTHR;
    for (uint32_t i = blockIdx.x * NTHR + threadIdx.x; i < G; i += stride) {
        uint32_t u = pairs[i].x & MASK31;
        atomicAdd(&lh[((u - uLo) >> shift1) & (CH_BINS - 1)], 1u);
    }
    __syncthreads();
    for (int i = threadIdx.x; i < CH_BINS; i += NTHR)
        if (lh[i]) atomicAdd(&ws[CH_OFF + i], lh[i]);
}

// ---- sub-bin select (redundant per block) + gather in-bin pairs -------------
__global__ void sel_gather_kernel(uint32_t* __restrict__ ws, uint32_t k) {
    __shared__ uint32_t lh[CH_BINS];
    __shared__ uint32_t csum[NTHR];
    __shared__ uint32_t cpre[NTHR];
    __shared__ uint32_t sBase2, sRem2, sKp;
    for (int i = threadIdx.x; i < CH_BINS; i += NTHR) lh[i] = ws[CH_OFF + i];
    __syncthreads();
    uint32_t s = 0;
    for (int i = 0; i < 16; ++i) s += lh[threadIdx.x * 16 + i];
    csum[threadIdx.x] = s;
    __syncthreads();
    if (threadIdx.x == 0) {
        uint32_t run = 0;
        for (int c = NTHR - 1; c >= 0; --c) { cpre[c] = run; run += csum[c]; }
        uint32_t cntHi = ws[SCL_OFF + 3];
        uint32_t total = cpre[0] + csum[0];
        uint32_t kp = (k > cntHi) ? (k - cntHi) : 1u;
        if (kp > total) kp = total;
        if (kp < 1u) kp = 1u;
        sKp = kp;
    }
    __syncthreads();
    uint32_t kp = sKp;
    if (cpre[threadIdx.x] < kp && kp <= cpre[threadIdx.x] + csum[threadIdx.x]) {
        uint32_t excl = cpre[threadIdx.x];
        for (int bb = threadIdx.x * 16 + 15; bb >= threadIdx.x * 16; --bb) {
            uint32_t cnt = lh[bb];
            if (excl + cnt >= kp) {
                sBase2 = ws[SCL_OFF + 0] + (((uint32_t)bb) << ws[SCL_OFF + 2]);
                sRem2 = kp - excl;
                break;
            }
            excl += cnt;
        }
    }
    __syncthreads();
    if (threadIdx.x == 0) { ws[SCL_OFF + 5] = sBase2; ws[SCL_OFF + 6] = sRem2; }
    uint32_t base2 = sBase2;
    uint32_t width = 1u << ws[SCL_OFF + 2];
    uint32_t G = ws[SCL_OFF + 4]; if (G > PAIRS_CAP) G = PAIRS_CAP;
    const uint2* pairs = (const uint2*)(ws + PAIRS_OFF);
    uint2* l3 = (uint2*)(ws + L3_OFF);
    uint32_t stride = gridDim.x * NTHR;
    for (uint32_t i = blockIdx.x * NTHR + threadIdx.x; i < G; i += stride) {
        uint2 pr = pairs[i];
        uint32_t u = pr.x & MASK31;
        if (u - base2 < width) {
            uint32_t p = atomicAdd(&ws[SCL_OFF + 7], 1u);
            if (p < L3_CAP) l3[p] = pr;
        }
    }
}

// ---- final fixup: restore above-sub-bin pairs; exact stable rank in-bin ----
__global__ void final_fixup_kernel(uint32_t* __restrict__ ws,
                                   uint32_t* __restrict__ out) {
    __shared__ uint2 l3s[L3_CAP];   // 32 KB
    uint32_t c3 = ws[SCL_OFF + 7]; if (c3 > L3_CAP) c3 = L3_CAP;
    uint32_t base2 = ws[SCL_OFF + 5], rem2 = ws[SCL_OFF + 6];
    uint32_t width = 1u << ws[SCL_OFF + 2];
    uint32_t tHi2 = base2 + width;
    const uint2* l3 = (const uint2*)(ws + L3_OFF);
    for (uint32_t q = threadIdx.x; q < c3; q += NTHR) l3s[q] = l3[q];
    __syncthreads();
    uint32_t G = ws[SCL_OFF + 4]; if (G > PAIRS_CAP) G = PAIRS_CAP;
    const uint2* pairs = (const uint2*)(ws + PAIRS_OFF);
    uint32_t stride = gridDim.x * NTHR;
    for (uint32_t i = blockIdx.x * NTHR + threadIdx.x; i < G; i += stride) {
        uint2 pr = pairs[i];
        uint32_t u = pr.x & MASK31;
        if (u >= tHi2) {
            out[pr.y] = pr.x;            // above sub-bin: definitely kept
        } else if (u - base2 < width) {  // in sub-bin: exact stable rank
            uint32_t rank = 0;
            for (uint32_t p = 0; p < c3; ++p) {
                uint2 q2 = l3s[p];
                uint32_t up = q2.x & MASK31;
                rank += (up > u || (up == u && q2.y < pr.y)) ? 1u : 0u;
            }
            if (rank < rem2) out[pr.y] = pr.x;
        }
    }
}

extern "C" void kernel_launch(void* const* d_in, const int* in_sizes, int n_in,
                              void* d_out, int out_size, void* d_ws, size_t ws_size,
                              hipStream_t stream) {
    const uint32_t* x = (const uint32_t*)d_in[0];
    uint32_t* out = (uint32_t*)d_out;
    uint32_t* ws = (uint32_t*)d_ws;
    long long n = (long long)in_sizes[0];

    const double ratio = 0.5;  // SPARSE_COMPRESSION_RATIO
    long long k = (long long)((double)n * (1.0 - ratio));
    if (k < 1) k = 1;
    if (k > n) k = n;

    long long n4 = n >> 2;
    long long S = (n4 >> 5) << 2;           // sampled elements (1/32 of n)
    long long ks = (long long)((double)k * ((double)S / (double)n));
    const long long M = 4500;               // ~9 sigma at S=1,048,576
    uint32_t ksmM = (uint32_t)((ks - M) < 1 ? 1 : (ks - M));
    uint32_t kspM = (uint32_t)((ks + M) > S ? S : (ks + M));

    // grid sized so the hot loop runs <= 16 iterations (fits 32-bit hit mask)
    long long nBlk = (n4 + (long long)NTHR * 16 - 1) / ((long long)NTHR * 16);
    if (nBlk < 1) nBlk = 1;
    if (nBlk > 8192) nBlk = 8192;
    int grid = (int)nBlk;

    zero_ws_kernel<<<(ZERO_WORDS + NTHR - 1) / NTHR, NTHR, 0, stream>>>(ws);
    sample_hist_kernel<<<512, NTHR, 0, stream>>>((const uint4*)x, n4, ws);
    sel_bracket_kernel<<<1, NTHR, 0, stream>>>(ws, ksmM, kspM);
    fused_main_kernel<<<grid, NTHR, 0, stream>>>(x, out, n, ws);
    cand_hist_kernel<<<256, NTHR, 0, stream>>>(ws);
    sel_gather_kernel<<<256, NTHR, 0, stream>>>(ws, (uint32_t)k);
    final_fixup_kernel<<<256, NTHR, 0, stream>>>(ws, out);
}

// Round 8
// 143.229 us; speedup vs baseline: 1.6589x; 1.0690x over previous
//
#include <hip/hip_runtime.h>
#include <stdint.h>

// ----------------------------------------------------------------------------
// SparseKVCache: keep top-k by |x| (k = n/2), zero the rest. Exact.
// R8: branchless fused pass with 4 independent load slots + NONTEMPORAL
// stores; rare bracket gather deferred to post-loop revisit of flagged
// iterations. Cheap coalesced sample pass (128 x 32KB chunks). Exact select
// on candidate set; stable ties (smallest indices) via rank fixup.
// ----------------------------------------------------------------------------

#define NTHR 256
#define MASK31 0x7fffffffu

typedef unsigned int v4u __attribute__((ext_vector_type(4)));

// ---- ws layout (uint32 words) ----
#define SH_OFF    0           // 8192-bin sample histogram (bits 30..18)
#define SH_BINS   8192
#define CH_OFF    8192        // 4096-bin candidate histogram
#define CH_BINS   4096
#define SCL_OFF   12288       // scalars:
//  [0]=uLo [1]=uHi [2]=shift1 [3]=cntHi [4]=gCount [5]=base2 [6]=rem2 [7]=c3
#define L3_OFF    12304       // sub-bin pairs (uint2); even => 8B aligned
#define L3_CAP    4096
#define PAIRS_OFF (L3_OFF + 2 * L3_CAP)    // 20496, even => 8B aligned
#define PAIRS_CAP (1u << 20)               // 1M pairs = 8 MB
#define ZERO_WORDS (SCL_OFF + 16)

#define STG_CAP   2048        // per-block LDS pair stage (16 KB)

__global__ void zero_ws_kernel(uint32_t* __restrict__ ws) {
    int i = blockIdx.x * blockDim.x + threadIdx.x;
    if (i < ZERO_WORDS) ws[i] = 0;
}

// ---- sample histogram: 128 blocks x 32KB contiguous chunks (1M samples) ----
__global__ void sample_hist_kernel(const uint4* __restrict__ xv, long long n4,
                                   uint32_t* __restrict__ ws) {
    __shared__ uint32_t lh[SH_BINS];
    for (int i = threadIdx.x; i < SH_BINS; i += NTHR) lh[i] = 0;
    __syncthreads();
    long long chunkStride = n4 >> 7;           // 128 chunks across the data
    long long base = (long long)blockIdx.x * chunkStride + threadIdx.x;
    for (int j = 0; j < 8; ++j) {
        long long idx = base + (long long)j * NTHR;
        if (idx < n4) {
            uint4 v = xv[idx];
            atomicAdd(&lh[(v.x & MASK31) >> 18], 1u);
            atomicAdd(&lh[(v.y & MASK31) >> 18], 1u);
            atomicAdd(&lh[(v.z & MASK31) >> 18], 1u);
            atomicAdd(&lh[(v.w & MASK31) >> 18], 1u);
        }
    }
    __syncthreads();
    for (int i = threadIdx.x; i < SH_BINS; i += NTHR)
        if (lh[i]) atomicAdd(&ws[SH_OFF + i], lh[i]);
}

// ---- bracket select from sample histogram -> value-space [uLo, uHi) --------
__global__ void sel_bracket_kernel(uint32_t* __restrict__ ws,
                                   uint32_t ksmM, uint32_t kspM) {
    __shared__ uint32_t lh[SH_BINS];
    __shared__ uint32_t csum[NTHR];
    __shared__ uint32_t cpre[NTHR];
    __shared__ int sBHi, sB1;
    for (int i = threadIdx.x; i < SH_BINS; i += NTHR) lh[i] = ws[SH_OFF + i];
    if (threadIdx.x == 0) { sBHi = -1; sB1 = -1; }
    __syncthreads();
    uint32_t s = 0;
    for (int i = 0; i < 32; ++i) s += lh[threadIdx.x * 32 + i];
    csum[threadIdx.x] = s;
    __syncthreads();
    if (threadIdx.x == 0) {
        uint32_t run = 0;
        for (int c = NTHR - 1; c >= 0; --c) { cpre[c] = run; run += csum[c]; }
    }
    __syncthreads();
    {
        int c = threadIdx.x;
        int hitHi = -1, hitB1 = -1;
        uint32_t excl = cpre[c];
        for (int bb = c * 32 + 31; bb >= c * 32; --bb) {
            uint32_t cnt = lh[bb];
            uint32_t incl = excl + cnt;
            if (hitHi < 0 && incl >= ksmM) hitHi = bb;
            if (hitB1 < 0 && excl >= kspM) hitB1 = bb;
            excl = incl;
        }
        if (hitHi >= 0) atomicMax(&sBHi, hitHi);
        if (hitB1 >= 0) atomicMax(&sB1, hitB1);
    }
    __syncthreads();
    if (threadIdx.x == 0) {
        int bHi = sBHi < 0 ? 0 : sBHi;
        int bLo = sB1 + 1;
        if (bLo > bHi) bLo = bHi;
        if (bLo < 0) bLo = 0;
        int sbins = bHi - bLo + 1;
        int clog = 0; while ((1 << clog) < sbins) ++clog;
        int spanBits = 18 + clog;
        int shift1 = spanBits - 12;            // 4096 bins over the span
        if (shift1 < 0) shift1 = 0;
        ws[SCL_OFF + 0] = ((uint32_t)bLo) << 18;          // uLo
        ws[SCL_OFF + 1] = ((uint32_t)(bHi + 1)) << 18;    // uHi (exclusive)
        ws[SCL_OFF + 2] = (uint32_t)shift1;
    }
}

// ---- fused full pass: 4-slot branchless stream, nt stores, deferred gather -
__global__ __launch_bounds__(NTHR, 4)
void fused_main_kernel(const uint32_t* __restrict__ x,
                       uint32_t* __restrict__ out, long long n,
                       uint32_t* __restrict__ ws) {
    __shared__ uint2 stage[STG_CAP];
    __shared__ uint32_t cnt, sBase, redHi[NTHR / 64];
    const uint32_t uLo = ws[SCL_OFF + 0];
    const uint32_t uHi = ws[SCL_OFF + 1];
    const uint32_t span = uHi - uLo;
    if (threadIdx.x == 0) cnt = 0u;
    __syncthreads();

    const v4u* __restrict__ xv = (const v4u*)x;
    v4u* __restrict__ ov = (v4u*)out;
    uint2* __restrict__ gpairs = (uint2*)(ws + PAIRS_OFF);
    long long n4 = n >> 2;
    const long long stride = (long long)gridDim.x * NTHR;
    const long long i0 = (long long)blockIdx.x * NTHR + threadIdx.x;

    uint32_t myHi = 0;
    uint32_t hitMask = 0;
    uint32_t it = 0;
    long long i = i0;

#define CLASS(v, o, hb) { \
    uint32_t c0 = v.x & MASK31, c1 = v.y & MASK31, c2 = v.z & MASK31, c3 = v.w & MASK31; \
    myHi += (uint32_t)(c0 >= uHi) + (uint32_t)(c1 >= uHi) \
          + (uint32_t)(c2 >= uHi) + (uint32_t)(c3 >= uHi); \
    o.x = (c0 >= uHi) ? v.x : 0u; o.y = (c1 >= uHi) ? v.y : 0u; \
    o.z = (c2 >= uHi) ? v.z : 0u; o.w = (c3 >= uHi) ? v.w : 0u; \
    hb = (uint32_t)((c0 - uLo) < span) | (uint32_t)((c1 - uLo) < span) \
       | (uint32_t)((c2 - uLo) < span) | (uint32_t)((c3 - uLo) < span); }

    // ---- hot loop: 4 independent loads -> branchless classify -> nt stores -
    for (; i + 3 * stride < n4; i += 4 * stride, it += 4) {
        v4u v0 = xv[i];
        v4u v1 = xv[i + stride];
        v4u v2 = xv[i + 2 * stride];
        v4u v3 = xv[i + 3 * stride];
        v4u o0, o1, o2, o3;
        uint32_t h0, h1, h2, h3;
        CLASS(v0, o0, h0) CLASS(v1, o1, h1) CLASS(v2, o2, h2) CLASS(v3, o3, h3)
        hitMask |= h0 << (it & 31);
        hitMask |= h1 << ((it + 1) & 31);
        hitMask |= h2 << ((it + 2) & 31);
        hitMask |= h3 << ((it + 3) & 31);
        __builtin_nontemporal_store(o0, &ov[i]);
        __builtin_nontemporal_store(o1, &ov[i + stride]);
        __builtin_nontemporal_store(o2, &ov[i + 2 * stride]);
        __builtin_nontemporal_store(o3, &ov[i + 3 * stride]);
    }
    for (; i < n4; i += stride, ++it) {     // remainder single slots
        v4u v = xv[i];
        v4u o;
        uint32_t hb;
        CLASS(v, o, hb)
        hitMask |= hb << (it & 31);
        __builtin_nontemporal_store(o, &ov[i]);
    }
#undef CLASS

#define PUSHP(val, eidx) { \
    uint32_t p_ = atomicAdd(&cnt, 1u); \
    uint2 pr_ = make_uint2((val), (eidx)); \
    if (p_ < STG_CAP) stage[p_] = pr_; \
    else { uint32_t g_ = atomicAdd(&ws[SCL_OFF + 4], 1u); \
           if (g_ < PAIRS_CAP) gpairs[g_] = pr_; } }

    // ---- scalar tail (n & 3), block 0 ----
    if (blockIdx.x == 0) {
        for (long long idx = (n4 << 2) + threadIdx.x; idx < n; idx += NTHR) {
            uint32_t v = x[idx];
            uint32_t u = v & MASK31;
            myHi += (uint32_t)(u >= uHi);
            if (u - uLo < span) PUSHP(v, (uint32_t)idx)
            out[idx] = (u >= uHi) ? v : 0u;
        }
    }

    // ---- rare path: revisit flagged iterations ----
    while (hitMask) {
        uint32_t b = __ffs(hitMask) - 1u;
        hitMask &= hitMask - 1u;
        for (long long ii = i0 + (long long)b * stride; ii < n4; ii += (stride << 5)) {
            v4u v = xv[ii];
            uint32_t e0 = (uint32_t)(ii << 2);
            uint32_t u;
            u = v.x & MASK31; if (u - uLo < span) PUSHP(v.x, e0 + 0u)
            u = v.y & MASK31; if (u - uLo < span) PUSHP(v.y, e0 + 1u)
            u = v.z & MASK31; if (u - uLo < span) PUSHP(v.z, e0 + 2u)
            u = v.w & MASK31; if (u - uLo < span) PUSHP(v.w, e0 + 3u)
        }
    }
#undef PUSHP

    // ---- block-level cntHi reduce: one global atomic per block ----
    for (int o = 32; o > 0; o >>= 1) myHi += __shfl_down(myHi, o);
    if ((threadIdx.x & 63) == 0) redHi[threadIdx.x >> 6] = myHi;
    __syncthreads();
    if (threadIdx.x == 0) {
        uint32_t tot = 0;
        for (int w = 0; w < NTHR / 64; ++w) tot += redHi[w];
        if (tot) atomicAdd(&ws[SCL_OFF + 3], tot);
        uint32_t c = cnt < STG_CAP ? cnt : STG_CAP;
        cnt = c;
        sBase = atomicAdd(&ws[SCL_OFF + 4], c);
    }
    __syncthreads();
    uint32_t c = cnt, bw = sBase;
    for (uint32_t q = threadIdx.x; q < c; q += NTHR)
        if (bw + q < PAIRS_CAP) gpairs[bw + q] = stage[q];
}

// ---- candidate histogram (4096 bins over bracket) ---------------------------
__global__ void cand_hist_kernel(uint32_t* __restrict__ ws) {
    __shared__ uint32_t lh[CH_BINS];
    uint32_t G = ws[SCL_OFF + 4]; if (G > PAIRS_CAP) G = PAIRS_CAP;
    uint32_t uLo = ws[SCL_OFF + 0], shift1 = ws[SCL_OFF + 2];
    for (int i = threadIdx.x; i < CH_BINS; i += NTHR) lh[i] = 0;
    __syncthreads();
    const uint2* pairs = (const uint2*)(ws + PAIRS_OFF);
    uint32_t stride = gridDim.x * NTHR;
    for (uint32_t i = blockIdx.x * NTHR + threadIdx.x; i < G; i += stride) {
        uint32_t u = pairs[i].x & MASK31;
        atomicAdd(&lh[((u - uLo) >> shift1) & (CH_BINS - 1)], 1u);
    }
    __syncthreads();
    for (int i = threadIdx.x; i < CH_BINS; i += NTHR)
        if (lh[i]) atomicAdd(&ws[CH_OFF + i], lh[i]);
}

// ---- sub-bin select (redundant per block) + gather in-bin pairs -------------
__global__ void sel_gather_kernel(uint32_t* __restrict__ ws, uint32_t k) {
    __shared__ uint32_t lh[CH_BINS];
    __shared__ uint32_t csum[NTHR];
    __shared__ uint32_t cpre[NTHR];
    __shared__ uint32_t sBase2, sRem2, sKp;
    for (int i = threadIdx.x; i < CH_BINS; i += NTHR) lh[i] = ws[CH_OFF + i];
    __syncthreads();
    uint32_t s = 0;
    for (int i = 0; i < 16; ++i) s += lh[threadIdx.x * 16 + i];
    csum[threadIdx.x] = s;
    __syncthreads();
    if (threadIdx.x == 0) {
        uint32_t run = 0;
        for (int c = NTHR - 1; c >= 0; --c) { cpre[c] = run; run += csum[c]; }
        uint32_t cntHi = ws[SCL_OFF + 3];
        uint32_t total = cpre[0] + csum[0];
        uint32_t kp = (k > cntHi) ? (k - cntHi) : 1u;
        if (kp > total) kp = total;
        if (kp < 1u) kp = 1u;
        sKp = kp;
    }
    __syncthreads();
    uint32_t kp = sKp;
    if (cpre[threadIdx.x] < kp && kp <= cpre[threadIdx.x] + csum[threadIdx.x]) {
        uint32_t excl = cpre[threadIdx.x];
        for (int bb = threadIdx.x * 16 + 15; bb >= threadIdx.x * 16; --bb) {
            uint32_t cnt = lh[bb];
            if (excl + cnt >= kp) {
                sBase2 = ws[SCL_OFF + 0] + (((uint32_t)bb) << ws[SCL_OFF + 2]);
                sRem2 = kp - excl;
                break;
            }
            excl += cnt;
        }
    }
    __syncthreads();
    if (threadIdx.x == 0) { ws[SCL_OFF + 5] = sBase2; ws[SCL_OFF + 6] = sRem2; }
    uint32_t base2 = sBase2;
    uint32_t width = 1u << ws[SCL_OFF + 2];
    uint32_t G = ws[SCL_OFF + 4]; if (G > PAIRS_CAP) G = PAIRS_CAP;
    const uint2* pairs = (const uint2*)(ws + PAIRS_OFF);
    uint2* l3 = (uint2*)(ws + L3_OFF);
    uint32_t stride = gridDim.x * NTHR;
    for (uint32_t i = blockIdx.x * NTHR + threadIdx.x; i < G; i += stride) {
        uint2 pr = pairs[i];
        uint32_t u = pr.x & MASK31;
        if (u - base2 < width) {
            uint32_t p = atomicAdd(&ws[SCL_OFF + 7], 1u);
            if (p < L3_CAP) l3[p] = pr;
        }
    }
}

// ---- final fixup: restore above-sub-bin pairs; exact stable rank in-bin ----
__global__ void final_fixup_kernel(uint32_t* __restrict__ ws,
                                   uint32_t* __restrict__ out) {
    __shared__ uint2 l3s[L3_CAP];   // 32 KB
    uint32_t c3 = ws[SCL_OFF + 7]; if (c3 > L3_CAP) c3 = L3_CAP;
    uint32_t base2 = ws[SCL_OFF + 5], rem2 = ws[SCL_OFF + 6];
    uint32_t width = 1u << ws[SCL_OFF + 2];
    uint32_t tHi2 = base2 + width;
    const uint2* l3 = (const uint2*)(ws + L3_OFF);
    for (uint32_t q = threadIdx.x; q < c3; q += NTHR) l3s[q] = l3[q];
    __syncthreads();
    uint32_t G = ws[SCL_OFF + 4]; if (G > PAIRS_CAP) G = PAIRS_CAP;
    const uint2* pairs = (const uint2*)(ws + PAIRS_OFF);
    uint32_t stride = gridDim.x * NTHR;
    for (uint32_t i = blockIdx.x * NTHR + threadIdx.x; i < G; i += stride) {
        uint2 pr = pairs[i];
        uint32_t u = pr.x & MASK31;
        if (u >= tHi2) {
            out[pr.y] = pr.x;            // above sub-bin: definitely kept
        } else if (u - base2 < width) {  // in sub-bin: exact stable rank
            uint32_t rank = 0;
            for (uint32_t p = 0; p < c3; ++p) {
                uint2 q2 = l3s[p];
                uint32_t up = q2.x & MASK31;
                rank += (up > u || (up == u && q2.y < pr.y)) ? 1u : 0u;
            }
            if (rank < rem2) out[pr.y] = pr.x;
        }
    }
}

extern "C" void kernel_launch(void* const* d_in, const int* in_sizes, int n_in,
                              void* d_out, int out_size, void* d_ws, size_t ws_size,
                              hipStream_t stream) {
    const uint32_t* x = (const uint32_t*)d_in[0];
    uint32_t* out = (uint32_t*)d_out;
    uint32_t* ws = (uint32_t*)d_ws;
    long long n = (long long)in_sizes[0];

    const double ratio = 0.5;  // SPARSE_COMPRESSION_RATIO
    long long k = (long long)((double)n * (1.0 - ratio));
    if (k < 1) k = 1;
    if (k > n) k = n;

    long long n4 = n >> 2;
    long long S = ((n4 >> 7) >= 2048) ? (128LL * NTHR * 8 * 4)   // 1M samples
                                      : (n4 << 2);
    long long ks = (long long)((double)k * ((double)S / (double)n));
    const long long M = 4500;               // ~9 sigma at S=1,048,576
    uint32_t ksmM = (uint32_t)((ks - M) < 1 ? 1 : (ks - M));
    uint32_t kspM = (uint32_t)((ks + M) > S ? S : (ks + M));

    // grid: <=32 hot-loop iterations so the hit mask fits 32 bits
    long long nBlk = (n4 + (long long)NTHR * 16 - 1) / ((long long)NTHR * 16);
    if (nBlk < 1) nBlk = 1;
    if (nBlk > 8192) nBlk = 8192;
    int grid = (int)nBlk;

    zero_ws_kernel<<<(ZERO_WORDS + NTHR - 1) / NTHR, NTHR, 0, stream>>>(ws);
    sample_hist_kernel<<<128, NTHR, 0, stream>>>((const uint4*)x, n4, ws);
    sel_bracket_kernel<<<1, NTHR, 0, stream>>>(ws, ksmM, kspM);
    fused_main_kernel<<<grid, NTHR, 0, stream>>>(x, out, n, ws);
    cand_hist_kernel<<<256, NTHR, 0, stream>>>(ws);
    sel_gather_kernel<<<256, NTHR, 0, stream>>>(ws, (uint32_t)k);
    final_fixup_kernel<<<256, NTHR, 0, stream>>>(ws, out);
}